// Round 1
// baseline (95.377 us; speedup 1.0000x reference)
//
#include <hip/hip_runtime.h>

// VQ-VAE VectorQuantizer, exploiting that h[p,:] = x[p]*w_in + b_in is affine in
// the scalar x[p]: dist_k(x) = ||h||^2 + a_k + x*m_k, so argmin over K codes is
// the lower envelope of 1024 lines -> per-pixel binary search over breakpoints.
//
// ws layout (doubles):
//   [0..1023]      A    = c_k - 2 r_k
//   [1024..2047]   M    = -2 p_k
//   [2048..3071]   T    = e_k . w_out
//   [3072..4095]   L    (interval left end per code)
//   [4096..5119]   R    (interval right end per code)
//   [5120..6143]   BP   (sorted breakpoints: BP[rank] = L of rank'th segment)
//   [6144..6151]   SC: W2, WB, B2, loss-accum
//   ints at (ws+6152): C[0..1023] = code of rank r; C[1024] = segment count S

#define VQ_K 1024
#define VQ_D 64
#define NPIX 262144  // 16*128*128

__global__ void k_coeff(const float* __restrict__ emb, const float* __restrict__ w_in,
                        const float* __restrict__ b_in, const float* __restrict__ w_out,
                        double* __restrict__ ws) {
    int k = blockIdx.x * blockDim.x + threadIdx.x;
    if (k < VQ_K) {
        const float* e = emb + k * VQ_D;
        double p = 0.0, r = 0.0, c = 0.0, t = 0.0;
        for (int d = 0; d < VQ_D; ++d) {
            double ed = (double)e[d];
            p += ed * (double)w_in[d];
            r += ed * (double)b_in[d];
            c += ed * ed;
            t += ed * (double)w_out[d];
        }
        ws[k]        = c - 2.0 * r;   // A
        ws[1024 + k] = -2.0 * p;      // M
        ws[2048 + k] = t;             // T
    }
    if (blockIdx.x == 0 && threadIdx.x == 0) {
        double W2 = 0.0, WB = 0.0, B2 = 0.0;
        for (int d = 0; d < VQ_D; ++d) {
            double w = (double)w_in[d], b = (double)b_in[d];
            W2 += w * w; WB += w * b; B2 += b * b;
        }
        ws[6144] = W2; ws[6145] = WB; ws[6146] = B2;
        ws[6147] = 0.0;  // loss accumulator (ws is re-poisoned each call)
    }
}

// For each code k: interval [L_k, R_k] of x where k is the argmin.
__global__ void k_interval(double* __restrict__ ws) {
    const double* A = ws;
    const double* M = ws + 1024;
    int k = blockIdx.x;
    double ak = A[k], mk = M[k];
    double lo = -1e300, hi = 1e300;
    int dom = 0;
    for (int j = threadIdx.x; j < VQ_K; j += 256) {
        if (j == k) continue;
        double aj = A[j], mj = M[j];
        if (mj == mk) {
            if (aj < ak || (aj == ak && j < k)) dom = 1;
        } else {
            double xx = (aj - ak) / (mk - mj);
            if (mj > mk) lo = fmax(lo, xx);
            else         hi = fmin(hi, xx);
        }
    }
    __shared__ double slo[256], shi[256];
    __shared__ int sd[256];
    slo[threadIdx.x] = lo; shi[threadIdx.x] = hi; sd[threadIdx.x] = dom;
    __syncthreads();
    for (int s = 128; s > 0; s >>= 1) {
        if (threadIdx.x < s) {
            slo[threadIdx.x] = fmax(slo[threadIdx.x], slo[threadIdx.x + s]);
            shi[threadIdx.x] = fmin(shi[threadIdx.x], shi[threadIdx.x + s]);
            sd[threadIdx.x] |= sd[threadIdx.x + s];
        }
        __syncthreads();
    }
    if (threadIdx.x == 0) {
        double L = slo[0], R = shi[0];
        if (sd[0]) { L = 1e300; R = -1e300; }
        ws[3072 + k] = L;
        ws[4096 + k] = R;
    }
}

// Rank valid segments by L, scatter code ids + breakpoints into sorted order.
__global__ void k_rank(double* __restrict__ ws) {
    const double* L = ws + 3072;
    const double* R = ws + 4096;
    int k = blockIdx.x;
    double lk = L[k];
    int validk = (lk < R[k]) ? 1 : 0;
    int less = 0, nvalid = 0;
    for (int j = threadIdx.x; j < VQ_K; j += 256) {
        double lj = L[j];
        int vj = (lj < R[j]) ? 1 : 0;
        nvalid += vj;
        if (vj && (lj < lk || (lj == lk && j < k))) less++;
    }
    __shared__ int sl[256], sv[256];
    sl[threadIdx.x] = less; sv[threadIdx.x] = nvalid;
    __syncthreads();
    for (int s = 128; s > 0; s >>= 1) {
        if (threadIdx.x < s) {
            sl[threadIdx.x] += sl[threadIdx.x + s];
            sv[threadIdx.x] += sv[threadIdx.x + s];
        }
        __syncthreads();
    }
    if (threadIdx.x == 0) {
        int* C = (int*)(ws + 6152);
        if (validk) {
            int r = sl[0];
            C[r] = k;
            ws[5120 + r] = lk;  // BP[r]
        }
        if (k == 0) C[1024] = sv[0];  // S
    }
}

__global__ __launch_bounds__(256) void k_main(const float* __restrict__ x,
                                              const float* __restrict__ b_out,
                                              double* __restrict__ ws,
                                              float* __restrict__ out) {
    __shared__ double sT[VQ_K], sBP[VQ_K], sA[VQ_K], sM[VQ_K];
    __shared__ int sC[VQ_K];
    __shared__ double red[4];
    for (int i = threadIdx.x; i < VQ_K; i += 256) {
        sA[i]  = ws[i];
        sM[i]  = ws[1024 + i];
        sT[i]  = ws[2048 + i];
        sBP[i] = ws[5120 + i];
        sC[i]  = ((const int*)(ws + 6152))[i];
    }
    int S = ((const int*)(ws + 6152))[1024];
    double W2 = ws[6144], WB = ws[6145], B2 = ws[6146];
    double bo = (double)b_out[0];
    __syncthreads();

    int pix = blockIdx.x * 256 + threadIdx.x;
    double xv = (double)x[pix];

    // largest i in [0, S) with BP[i] <= xv  (BP[0] = -1e300)
    int lo = 0, hi = S - 1;
    while (lo < hi) {
        int mid = (lo + hi + 1) >> 1;
        if (sBP[mid] <= xv) lo = mid; else hi = mid - 1;
    }
    int k = sC[lo];

    out[pix] = (float)(sT[k] + bo);

    // per-pixel distance = sum_d (e_kd - h_d)^2 = a_k + x m_k + x^2 W2 + 2x WB + B2
    double s = sA[k] + xv * sM[k] + xv * xv * W2 + 2.0 * xv * WB + B2;

    // wave (64-lane) shuffle reduction, then cross-wave via LDS
    for (int off = 32; off > 0; off >>= 1) s += __shfl_down(s, off, 64);
    int lane = threadIdx.x & 63, wid = threadIdx.x >> 6;
    if (lane == 0) red[wid] = s;
    __syncthreads();
    if (threadIdx.x == 0) {
        double bs = red[0] + red[1] + red[2] + red[3];
        atomicAdd(&ws[6147], bs);
    }
}

__global__ void k_final(const double* __restrict__ ws, float* __restrict__ out) {
    // emb_loss = 10 * (0.25 + 1) * mean((q-h)^2) over 16*128*128*64 elements
    out[NPIX] = (float)(12.5 * ws[6147] / 16777216.0);
}

extern "C" void kernel_launch(void* const* d_in, const int* in_sizes, int n_in,
                              void* d_out, int out_size, void* d_ws, size_t ws_size,
                              hipStream_t stream) {
    const float* x     = (const float*)d_in[0];
    const float* w_in  = (const float*)d_in[1];
    const float* b_in  = (const float*)d_in[2];
    const float* emb   = (const float*)d_in[3];
    const float* w_out = (const float*)d_in[4];
    const float* b_out = (const float*)d_in[5];
    float* out = (float*)d_out;
    double* ws = (double*)d_ws;

    hipLaunchKernelGGL(k_coeff,    dim3(4),    dim3(256), 0, stream, emb, w_in, b_in, w_out, ws);
    hipLaunchKernelGGL(k_interval, dim3(VQ_K), dim3(256), 0, stream, ws);
    hipLaunchKernelGGL(k_rank,     dim3(VQ_K), dim3(256), 0, stream, ws);
    hipLaunchKernelGGL(k_main,     dim3(NPIX / 256), dim3(256), 0, stream, x, b_out, ws, out);
    hipLaunchKernelGGL(k_final,    dim3(1),    dim3(1),   0, stream, ws, out);
}

// Round 2
// 82.994 us; speedup vs baseline: 1.1492x; 1.1492x over previous
//
#include <hip/hip_runtime.h>
#include <hip/hip_bf16.h>

// VQ-VAE VectorQuantizer on MI355X.
// Key identity: h[p,:] = x[p]*w_in + b_in is affine in the SCALAR x[p], so
//   dist_k(x) = ||h||^2 + (||e_k||^2 - 2 b_in.e_k) + x * (-2 w_in.e_k)
//             = const(x) + A_k + x*M_k.
// argmin_k is the lower envelope of K=1024 lines. Only S (~tens) lines ever
// win; we find them by pairwise interval intersection (exact f64), compact
// them unordered, and each pixel takes argmin BY VALUE over the S survivors.
//
// ws layout (doubles):
//   [0..1023]      A_k = ||e_k||^2 - 2 b.e_k
//   [1024..2047]   M_k = -2 w.e_k
//   [2048..3071]   T_k = e_k . w_out
//   [3072..4095]   cA  (compacted A of valid envelope lines)
//   [4096..5119]   cM
//   [5120..6143]   cT
//   [6144] W2=||w||^2  [6145] WB=w.b  [6146] B2=||b||^2  [6147] loss accum
//   ints at (ws+6148): [0] = S (valid-count/slot counter), [1] = done-counter

#define VQ_K 1024
#define VQ_D 64
#define NPIX 262144  // 16*128*128

__global__ void k_prep(const float* __restrict__ emb, const float* __restrict__ w_in,
                       const float* __restrict__ b_in, const float* __restrict__ w_out,
                       double* __restrict__ ws) {
    int k = blockIdx.x * blockDim.x + threadIdx.x;
    if (k < VQ_K) {
        const float* e = emb + k * VQ_D;
        double p = 0.0, r = 0.0, c = 0.0, t = 0.0;
        for (int d = 0; d < VQ_D; ++d) {
            double ed = (double)e[d];
            p += ed * (double)w_in[d];
            r += ed * (double)b_in[d];
            c += ed * ed;
            t += ed * (double)w_out[d];
        }
        ws[k]        = c - 2.0 * r;   // A
        ws[1024 + k] = -2.0 * p;      // M
        ws[2048 + k] = t;             // T
    }
    if (blockIdx.x == 0 && threadIdx.x == 0) {
        double W2 = 0.0, WB = 0.0, B2 = 0.0;
        for (int d = 0; d < VQ_D; ++d) {
            double w = (double)w_in[d], b = (double)b_in[d];
            W2 += w * w; WB += w * b; B2 += b * b;
        }
        ws[6144] = W2; ws[6145] = WB; ws[6146] = B2;
        ws[6147] = 0.0;                    // loss accumulator
        int* cnt = (int*)(ws + 6148);
        cnt[0] = 0;                        // S (compaction slot counter)
        cnt[1] = 0;                        // done-counter
    }
}

// Block k: interval [lo,hi] where line k is minimal; if nonempty, grab a
// compaction slot and store (A,M,T) there (order irrelevant).
__global__ void k_env(double* __restrict__ ws) {
    const double* A = ws;
    const double* M = ws + 1024;
    int k = blockIdx.x;
    double ak = A[k], mk = M[k];
    double lo = -1e300, hi = 1e300;
    int dom = 0;
    for (int j = threadIdx.x; j < VQ_K; j += 256) {
        if (j == k) continue;
        double aj = A[j], mj = M[j];
        if (mj == mk) {
            if (aj < ak || (aj == ak && j < k)) dom = 1;  // identical-slope dominance
        } else {
            double xx = (aj - ak) / (mk - mj);            // crossing point
            if (mj > mk) lo = fmax(lo, xx);
            else         hi = fmin(hi, xx);
        }
    }
    __shared__ double slo[256], shi[256];
    __shared__ int sd[256];
    slo[threadIdx.x] = lo; shi[threadIdx.x] = hi; sd[threadIdx.x] = dom;
    __syncthreads();
    for (int s = 128; s > 0; s >>= 1) {
        if (threadIdx.x < s) {
            slo[threadIdx.x] = fmax(slo[threadIdx.x], slo[threadIdx.x + s]);
            shi[threadIdx.x] = fmin(shi[threadIdx.x], shi[threadIdx.x + s]);
            sd[threadIdx.x] |= sd[threadIdx.x + s];
        }
        __syncthreads();
    }
    if (threadIdx.x == 0 && !sd[0] && slo[0] < shi[0]) {
        int* cnt = (int*)(ws + 6148);
        int s = atomicAdd(&cnt[0], 1);
        ws[3072 + s] = ak;
        ws[4096 + s] = mk;
        ws[5120 + s] = ws[2048 + k];
    }
}

// 256 blocks x 256 threads x 4 pixels/thread (float4). Argmin by value over
// the S compacted lines; fused loss reduction; last block writes the scalar.
__global__ __launch_bounds__(256) void k_pix(const float* __restrict__ x,
                                             const float* __restrict__ b_out,
                                             double* __restrict__ ws,
                                             float* __restrict__ out) {
    __shared__ double sA[VQ_K], sM[VQ_K], sT[VQ_K];
    __shared__ double red[4];
    int* cnt = (int*)(ws + 6148);
    int S = cnt[0];
    for (int i = threadIdx.x; i < S; i += 256) {
        sA[i] = ws[3072 + i];
        sM[i] = ws[4096 + i];
        sT[i] = ws[5120 + i];
    }
    double W2 = ws[6144], WB = ws[6145], B2 = ws[6146];
    double bo = (double)b_out[0];
    __syncthreads();

    int gid = blockIdx.x * 256 + threadIdx.x;       // 65536 threads
    float4 xv4 = ((const float4*)x)[gid];
    double xv[4] = {(double)xv4.x, (double)xv4.y, (double)xv4.z, (double)xv4.w};
    double best[4] = {1e300, 1e300, 1e300, 1e300};
    double bt[4]   = {0.0, 0.0, 0.0, 0.0};

    for (int s = 0; s < S; ++s) {
        double a = sA[s], m = sM[s], t = sT[s];
        #pragma unroll
        for (int p = 0; p < 4; ++p) {
            double v = fma(xv[p], m, a);
            if (v < best[p]) { best[p] = v; bt[p] = t; }
        }
    }

    float4 o;
    o.x = (float)(bt[0] + bo);
    o.y = (float)(bt[1] + bo);
    o.z = (float)(bt[2] + bo);
    o.w = (float)(bt[3] + bo);
    ((float4*)out)[gid] = o;

    // dist_p = best_p + x^2 W2 + 2x WB + B2 ; sum over the 4 pixels
    double s = 0.0;
    #pragma unroll
    for (int p = 0; p < 4; ++p)
        s += best[p] + xv[p] * xv[p] * W2 + 2.0 * xv[p] * WB + B2;

    for (int off = 32; off > 0; off >>= 1) s += __shfl_down(s, off, 64);
    int lane = threadIdx.x & 63, wid = threadIdx.x >> 6;
    if (lane == 0) red[wid] = s;
    __syncthreads();
    if (threadIdx.x == 0) {
        double bs = red[0] + red[1] + red[2] + red[3];
        atomicAdd(&ws[6147], bs);
        __threadfence();
        int old = atomicAdd(&cnt[1], 1);
        if (old == (int)gridDim.x - 1) {
            double total = atomicAdd(&ws[6147], 0.0);  // coherent read-back
            // emb_loss = 10*(0.25+1)*mean((q-h)^2), mean over 2^24 elements
            out[NPIX] = (float)(12.5 * total / 16777216.0);
        }
    }
}

extern "C" void kernel_launch(void* const* d_in, const int* in_sizes, int n_in,
                              void* d_out, int out_size, void* d_ws, size_t ws_size,
                              hipStream_t stream) {
    const float* x     = (const float*)d_in[0];
    const float* w_in  = (const float*)d_in[1];
    const float* b_in  = (const float*)d_in[2];
    const float* emb   = (const float*)d_in[3];
    const float* w_out = (const float*)d_in[4];
    const float* b_out = (const float*)d_in[5];
    float* out = (float*)d_out;
    double* ws = (double*)d_ws;

    hipLaunchKernelGGL(k_prep, dim3(4),         dim3(256), 0, stream, emb, w_in, b_in, w_out, ws);
    hipLaunchKernelGGL(k_env,  dim3(VQ_K),      dim3(256), 0, stream, ws);
    hipLaunchKernelGGL(k_pix,  dim3(NPIX/1024), dim3(256), 0, stream, x, b_out, ws, out);
}